// Round 1
// baseline (2464.204 us; speedup 1.0000x reference)
//
#include <hip/hip_runtime.h>
#include <hip/hip_bf16.h>

#define HDIM 128

// deg[i] = 1.0 (self loop)
__global__ void deg_init_k(float* __restrict__ deg, int N) {
    int i = blockIdx.x * blockDim.x + threadIdx.x;
    if (i < N) deg[i] = 1.0f;
}

// deg[dst[e]] += 1
__global__ void deg_count_k(const int* __restrict__ dst, float* __restrict__ deg, int E) {
    int i = blockIdx.x * blockDim.x + threadIdx.x;
    if (i < E) atomicAdd(&deg[dst[i]], 1.0f);
}

// deg -> rsqrt(deg) in place (deg >= 1 always due to self loop)
__global__ void deg_rsqrt_k(float* __restrict__ deg, int N) {
    int i = blockIdx.x * blockDim.x + threadIdx.x;
    if (i < N) deg[i] = rsqrtf(deg[i]);
}

// hs = (X @ W) * dis[row];  optionally also duplicate into agg (self-loop init)
__global__ __launch_bounds__(128) void gemm_scale_k(
    const float* __restrict__ X, const float* __restrict__ W,
    const float* __restrict__ dis, float* __restrict__ hs,
    float* __restrict__ agg, int N) {
    __shared__ float Wl[HDIM * HDIM];   // 64 KB
    __shared__ float xs[4][HDIM];
    const int tid = threadIdx.x;  // 128 threads
    for (int i = tid; i < HDIM * HDIM; i += 128) Wl[i] = W[i];

    const int nquad = (N + 3) >> 2;
    for (int q = blockIdx.x; q < nquad; q += gridDim.x) {
        const int row0 = q << 2;
        __syncthreads();  // protects Wl load on first iter, xs reuse after
        #pragma unroll
        for (int r = 0; r < 4; ++r) {
            int row = row0 + r;
            xs[r][tid] = (row < N) ? X[row * HDIM + tid] : 0.0f;
        }
        __syncthreads();
        float acc0 = 0.f, acc1 = 0.f, acc2 = 0.f, acc3 = 0.f;
        #pragma unroll
        for (int k = 0; k < HDIM; ++k) {
            const float w = Wl[k * HDIM + tid];
            acc0 += xs[0][k] * w;
            acc1 += xs[1][k] * w;
            acc2 += xs[2][k] * w;
            acc3 += xs[3][k] * w;
        }
        #pragma unroll
        for (int r = 0; r < 4; ++r) {
            int row = row0 + r;
            if (row < N) {
                float acc = (r == 0) ? acc0 : (r == 1) ? acc1 : (r == 2) ? acc2 : acc3;
                float v = acc * dis[row];
                hs[row * HDIM + tid] = v;
                if (agg) agg[row * HDIM + tid] = v;
            }
        }
    }
}

// d2d copy, float4
__global__ void copy_k(const float* __restrict__ src, float* __restrict__ dst, long total4) {
    long i = blockIdx.x * (long)blockDim.x + threadIdx.x;
    const long stride = (long)gridDim.x * blockDim.x;
    for (; i < total4; i += stride)
        reinterpret_cast<float4*>(dst)[i] = reinterpret_cast<const float4*>(src)[i];
}

// agg[dst[e]][:] += hs[src[e]][:]   (32 lanes per edge, float4 each)
__global__ void scatter_k(const int* __restrict__ src, const int* __restrict__ dst,
                          const float* __restrict__ hs, float* __restrict__ agg, int E) {
    long i = blockIdx.x * (long)blockDim.x + threadIdx.x;
    const long total = (long)E * 32;
    const long stride = (long)gridDim.x * blockDim.x;
    for (; i < total; i += stride) {
        const int e = (int)(i >> 5);
        const int c = ((int)i & 31) << 2;
        const int s = src[e], d = dst[e];
        const float4 v = *reinterpret_cast<const float4*>(&hs[s * HDIM + c]);
        float* p = &agg[d * HDIM + c];
        atomicAdd(p + 0, v.x);
        atomicAdd(p + 1, v.y);
        atomicAdd(p + 2, v.z);
        atomicAdd(p + 3, v.w);
    }
}

// out = relu(dis[row] * agg + b)
__global__ void finish_k(const float* __restrict__ agg, const float* __restrict__ dis,
                         const float* __restrict__ b, float* __restrict__ out, int N) {
    long i = blockIdx.x * (long)blockDim.x + threadIdx.x;
    const long total = (long)N * 32;  // float4 granules
    const long stride = (long)gridDim.x * blockDim.x;
    for (; i < total; i += stride) {
        const int row = (int)(i >> 5);
        const int c = ((int)i & 31) << 2;
        const float dv = dis[row];
        const float4 a = *reinterpret_cast<const float4*>(&agg[row * HDIM + c]);
        const float4 bb = *reinterpret_cast<const float4*>(&b[c]);
        float4 o;
        o.x = fmaxf(fmaf(a.x, dv, bb.x), 0.f);
        o.y = fmaxf(fmaf(a.y, dv, bb.y), 0.f);
        o.z = fmaxf(fmaf(a.z, dv, bb.z), 0.f);
        o.w = fmaxf(fmaf(a.w, dv, bb.w), 0.f);
        *reinterpret_cast<float4*>(&out[row * HDIM + c]) = o;
    }
}

// q[a] = sum_j h[u][j]*Wq[j] + h[v][j]*Wq[128+j] + bq   (one wave64 per action)
__global__ void qhead_k(const float* __restrict__ h, const int* __restrict__ va,
                        const float* __restrict__ Wq, const float* __restrict__ bq,
                        float* __restrict__ out, int A) {
    const int lane = threadIdx.x & 63;
    int w = (int)((blockIdx.x * (long)blockDim.x + threadIdx.x) >> 6);
    const int nw = (int)(((long)gridDim.x * blockDim.x) >> 6);
    const float2 wu = *reinterpret_cast<const float2*>(&Wq[lane * 2]);
    const float2 wv = *reinterpret_cast<const float2*>(&Wq[HDIM + lane * 2]);
    const float bqv = bq[0];
    for (int a = w; a < A; a += nw) {
        const int u = va[2 * a], v = va[2 * a + 1];
        const float2 hu = *reinterpret_cast<const float2*>(&h[u * HDIM + lane * 2]);
        const float2 hv = *reinterpret_cast<const float2*>(&h[v * HDIM + lane * 2]);
        float s = hu.x * wu.x + hu.y * wu.y + hv.x * wv.x + hv.y * wv.y;
        #pragma unroll
        for (int off = 32; off > 0; off >>= 1) s += __shfl_down(s, off, 64);
        if (lane == 0) out[a] = s + bqv;
    }
}

extern "C" void kernel_launch(void* const* d_in, const int* in_sizes, int n_in,
                              void* d_out, int out_size, void* d_ws, size_t ws_size,
                              hipStream_t stream) {
    const float* x   = (const float*)d_in[0];
    const int*   ei  = (const int*)d_in[1];     // [2][E] flat: src then dst
    const int*   va  = (const int*)d_in[2];     // [A][2]
    const float* W1  = (const float*)d_in[3];
    const float* b1  = (const float*)d_in[4];
    const float* W2  = (const float*)d_in[5];
    const float* b2  = (const float*)d_in[6];
    const float* Wq  = (const float*)d_in[7];
    const float* bq  = (const float*)d_in[8];
    float* out = (float*)d_out;

    const int N = in_sizes[0] / HDIM;       // 50000
    const int E = in_sizes[1] / 2;          // 600000
    const int A = in_sizes[2] / 2;          // 200000
    const int* esrc = ei;
    const int* edst = ei + E;

    float* dis  = (float*)d_ws;                    // N floats
    float* bufA = dis + ((N + 3) & ~3);            // N*128
    float* bufB = bufA + (long)N * HDIM;           // N*128

    const int T = 256;
    // --- degree / norm ---
    deg_init_k<<<(N + T - 1) / T, T, 0, stream>>>(dis, N);
    deg_count_k<<<(E + T - 1) / T, T, 0, stream>>>(edst, dis, E);
    deg_rsqrt_k<<<(N + T - 1) / T, T, 0, stream>>>(dis, N);

    // --- layer 1 ---
    gemm_scale_k<<<512, 128, 0, stream>>>(x, W1, dis, bufA, bufB, N);   // hs + agg-init
    scatter_k<<<6144, T, 0, stream>>>(esrc, edst, bufA, bufB, E);
    finish_k<<<2048, T, 0, stream>>>(bufB, dis, b1, bufA, N);           // h1 -> bufA

    // --- layer 2 ---
    gemm_scale_k<<<512, 128, 0, stream>>>(bufA, W2, dis, bufB, nullptr, N); // hs2 -> bufB
    copy_k<<<2048, T, 0, stream>>>(bufB, bufA, (long)N * HDIM / 4);     // agg-init -> bufA
    scatter_k<<<6144, T, 0, stream>>>(esrc, edst, bufB, bufA, E);
    finish_k<<<2048, T, 0, stream>>>(bufA, dis, b2, bufB, N);           // h2 -> bufB

    // --- Q head ---
    qhead_k<<<4096, T, 0, stream>>>(bufB, va, Wq, bq, out, A);
}

// Round 2
// 563.408 us; speedup vs baseline: 4.3737x; 4.3737x over previous
//
#include <hip/hip_runtime.h>
#include <hip/hip_bf16.h>

#define HDIM 128

// ---------- CSR build ----------

// deg_i[dst[e]] += 1  (int atomics)
__global__ void deg_count_k(const int* __restrict__ dst, int* __restrict__ deg, int E) {
    int i = blockIdx.x * blockDim.x + threadIdx.x;
    if (i < E) atomicAdd(&deg[dst[i]], 1);
}

// per-256-block inclusive scan; emit inclusive partials + block totals
__global__ void scan_part_k(const int* __restrict__ deg, int* __restrict__ incl,
                            int* __restrict__ blocksum, int N) {
    __shared__ int s[256];
    const int tid = threadIdx.x;
    const int i = blockIdx.x * 256 + tid;
    int v = (i < N) ? deg[i] : 0;
    s[tid] = v;
    __syncthreads();
    #pragma unroll
    for (int off = 1; off < 256; off <<= 1) {
        int t = (tid >= off) ? s[tid - off] : 0;
        __syncthreads();
        s[tid] += t;
        __syncthreads();
    }
    if (i < N) incl[i] = s[tid];
    if (tid == 255) blocksum[blockIdx.x] = s[255];
}

// exclusive-scan blocksum in place (NB <= 256)
__global__ void scan_block_k(int* __restrict__ blocksum, int NB) {
    __shared__ int s[256];
    const int tid = threadIdx.x;
    int v = (tid < NB) ? blocksum[tid] : 0;
    s[tid] = v;
    __syncthreads();
    #pragma unroll
    for (int off = 1; off < 256; off <<= 1) {
        int t = (tid >= off) ? s[tid - off] : 0;
        __syncthreads();
        s[tid] += t;
        __syncthreads();
    }
    if (tid < NB) blocksum[tid] = s[tid] - v;   // exclusive
}

// rowptr[i] = excl_prefix; dis[i] = rsqrt(deg+1); rowptr[N] = E
__global__ void scan_final_k(const int* __restrict__ deg, const int* __restrict__ incl,
                             const int* __restrict__ blocksum, int* __restrict__ rowptr,
                             float* __restrict__ dis, int N, int E) {
    const int i = blockIdx.x * 256 + threadIdx.x;
    if (i < N) {
        rowptr[i] = blocksum[blockIdx.x] + incl[i] - deg[i];
        dis[i] = rsqrtf((float)deg[i] + 1.0f);
    }
    if (i == 0) rowptr[N] = E;
}

// csr[rowptr[dst] + cursor[dst]++] = src
__global__ void fill_csr_k(const int* __restrict__ src, const int* __restrict__ dst,
                           const int* __restrict__ rowptr, int* __restrict__ cursor,
                           int* __restrict__ csr, int E) {
    int e = blockIdx.x * blockDim.x + threadIdx.x;
    if (e < E) {
        const int d = dst[e];
        const int pos = rowptr[d] + atomicAdd(&cursor[d], 1);
        csr[pos] = src[e];
    }
}

// ---------- GCN layer ----------

// hs = (X @ W) * dis[row]
__global__ __launch_bounds__(128) void gemm_scale_k(
    const float* __restrict__ X, const float* __restrict__ W,
    const float* __restrict__ dis, float* __restrict__ hs, int N) {
    __shared__ float Wl[HDIM * HDIM];   // 64 KB
    __shared__ float xs[4][HDIM];
    const int tid = threadIdx.x;  // 128 threads
    for (int i = tid; i < HDIM * HDIM; i += 128) Wl[i] = W[i];

    const int nquad = (N + 3) >> 2;
    for (int q = blockIdx.x; q < nquad; q += gridDim.x) {
        const int row0 = q << 2;
        __syncthreads();  // protects Wl on first iter, xs reuse after
        #pragma unroll
        for (int r = 0; r < 4; ++r) {
            int row = row0 + r;
            xs[r][tid] = (row < N) ? X[row * HDIM + tid] : 0.0f;
        }
        __syncthreads();
        float acc0 = 0.f, acc1 = 0.f, acc2 = 0.f, acc3 = 0.f;
        #pragma unroll
        for (int k = 0; k < HDIM; ++k) {
            const float w = Wl[k * HDIM + tid];
            acc0 += xs[0][k] * w;
            acc1 += xs[1][k] * w;
            acc2 += xs[2][k] * w;
            acc3 += xs[3][k] * w;
        }
        #pragma unroll
        for (int r = 0; r < 4; ++r) {
            int row = row0 + r;
            if (row < N) {
                float acc = (r == 0) ? acc0 : (r == 1) ? acc1 : (r == 2) ? acc2 : acc3;
                hs[row * HDIM + tid] = acc * dis[row];
            }
        }
    }
}

// one wave per node: acc = hs[n] + sum_e hs[csr[e]];  out = relu(dis[n]*acc + b)
__global__ __launch_bounds__(256) void gather_agg_k(
    const int* __restrict__ rowptr, const int* __restrict__ csr,
    const float* __restrict__ hs, const float* __restrict__ dis,
    const float* __restrict__ b, float* __restrict__ out, int N) {
    const int lane = threadIdx.x & 63;
    const int wid = (int)((blockIdx.x * (long)blockDim.x + threadIdx.x) >> 6);
    const int nw = (int)(((long)gridDim.x * blockDim.x) >> 6);
    const float2 bb = *reinterpret_cast<const float2*>(&b[lane * 2]);
    for (int n = wid; n < N; n += nw) {
        const int r0 = rowptr[n], r1 = rowptr[n + 1];
        float2 acc = *reinterpret_cast<const float2*>(&hs[(long)n * HDIM + lane * 2]);
        int e = r0;
        for (; e + 2 <= r1; e += 2) {
            const int s0 = csr[e], s1 = csr[e + 1];
            const float2 v0 = *reinterpret_cast<const float2*>(&hs[(long)s0 * HDIM + lane * 2]);
            const float2 v1 = *reinterpret_cast<const float2*>(&hs[(long)s1 * HDIM + lane * 2]);
            acc.x += v0.x + v1.x;
            acc.y += v0.y + v1.y;
        }
        if (e < r1) {
            const int s0 = csr[e];
            const float2 v0 = *reinterpret_cast<const float2*>(&hs[(long)s0 * HDIM + lane * 2]);
            acc.x += v0.x;
            acc.y += v0.y;
        }
        const float dv = dis[n];
        float2 o;
        o.x = fmaxf(fmaf(acc.x, dv, bb.x), 0.f);
        o.y = fmaxf(fmaf(acc.y, dv, bb.y), 0.f);
        *reinterpret_cast<float2*>(&out[(long)n * HDIM + lane * 2]) = o;
    }
}

// q[a] = sum_j h[u][j]*Wq[j] + h[v][j]*Wq[128+j] + bq   (one wave64 per action)
__global__ void qhead_k(const float* __restrict__ h, const int* __restrict__ va,
                        const float* __restrict__ Wq, const float* __restrict__ bq,
                        float* __restrict__ out, int A) {
    const int lane = threadIdx.x & 63;
    int w = (int)((blockIdx.x * (long)blockDim.x + threadIdx.x) >> 6);
    const int nw = (int)(((long)gridDim.x * blockDim.x) >> 6);
    const float2 wu = *reinterpret_cast<const float2*>(&Wq[lane * 2]);
    const float2 wv = *reinterpret_cast<const float2*>(&Wq[HDIM + lane * 2]);
    const float bqv = bq[0];
    for (int a = w; a < A; a += nw) {
        const int u = va[2 * a], v = va[2 * a + 1];
        const float2 hu = *reinterpret_cast<const float2*>(&h[(long)u * HDIM + lane * 2]);
        const float2 hv = *reinterpret_cast<const float2*>(&h[(long)v * HDIM + lane * 2]);
        float s = hu.x * wu.x + hu.y * wu.y + hv.x * wv.x + hv.y * wv.y;
        #pragma unroll
        for (int off = 32; off > 0; off >>= 1) s += __shfl_down(s, off, 64);
        if (lane == 0) out[a] = s + bqv;
    }
}

extern "C" void kernel_launch(void* const* d_in, const int* in_sizes, int n_in,
                              void* d_out, int out_size, void* d_ws, size_t ws_size,
                              hipStream_t stream) {
    const float* x   = (const float*)d_in[0];
    const int*   ei  = (const int*)d_in[1];     // [2][E] flat: src then dst
    const int*   va  = (const int*)d_in[2];     // [A][2]
    const float* W1  = (const float*)d_in[3];
    const float* b1  = (const float*)d_in[4];
    const float* W2  = (const float*)d_in[5];
    const float* b2  = (const float*)d_in[6];
    const float* Wq  = (const float*)d_in[7];
    const float* bq  = (const float*)d_in[8];
    float* out = (float*)d_out;

    const int N = in_sizes[0] / HDIM;       // 50000
    const int E = in_sizes[1] / 2;          // 600000
    const int A = in_sizes[2] / 2;          // 200000
    const int* esrc = ei;
    const int* edst = ei + E;

    const int Nal = (N + 15) & ~15;
    const int Eal = (E + 15) & ~15;

    int*   deg_i    = (int*)d_ws;            // N
    int*   incl     = deg_i + Nal;           // N
    int*   rowptr   = incl + Nal;            // N+1
    int*   cursor   = rowptr + Nal + 16;     // N
    int*   blocksum = cursor + Nal;          // 256
    int*   csr      = blocksum + 256;        // E
    float* dis      = (float*)(csr + Eal);   // N
    float* bufA     = dis + Nal;             // N*128
    float* bufB     = bufA + (long)N * HDIM; // N*128

    const int T = 256;
    const int NB = (N + 255) / 256;          // 196 blocks (<= 256 required)

    // --- CSR build + norms ---
    hipMemsetAsync(deg_i, 0, (size_t)N * sizeof(int), stream);
    hipMemsetAsync(cursor, 0, (size_t)N * sizeof(int), stream);
    deg_count_k<<<(E + T - 1) / T, T, 0, stream>>>(edst, deg_i, E);
    scan_part_k<<<NB, 256, 0, stream>>>(deg_i, incl, blocksum, N);
    scan_block_k<<<1, 256, 0, stream>>>(blocksum, NB);
    scan_final_k<<<NB, 256, 0, stream>>>(deg_i, incl, blocksum, rowptr, dis, N, E);
    fill_csr_k<<<(E + T - 1) / T, T, 0, stream>>>(esrc, edst, rowptr, cursor, csr, E);

    // --- layer 1 ---
    gemm_scale_k<<<512, 128, 0, stream>>>(x, W1, dis, bufA, N);
    gather_agg_k<<<2048, T, 0, stream>>>(rowptr, csr, bufA, dis, b1, bufB, N);

    // --- layer 2 ---
    gemm_scale_k<<<512, 128, 0, stream>>>(bufB, W2, dis, bufA, N);
    gather_agg_k<<<2048, T, 0, stream>>>(rowptr, csr, bufA, dis, b2, bufB, N);

    // --- Q head ---
    qhead_k<<<4096, T, 0, stream>>>(bufB, va, Wq, bq, out, A);
}

// Round 3
// 321.398 us; speedup vs baseline: 7.6671x; 1.7530x over previous
//
#include <hip/hip_runtime.h>
#include <hip/hip_bf16.h>

#define HDIM 128

typedef __attribute__((ext_vector_type(8))) short bf16x8_t;
typedef __attribute__((ext_vector_type(4))) float f32x4_t;

// ---------- helpers ----------
__device__ inline float bf16u_to_f(unsigned int u) { return __uint_as_float(u << 16); }
__device__ inline unsigned short bf16_rne(float x) {
    union { __hip_bfloat16 b; unsigned short u; } cv;
    cv.b = __float2bfloat16(x);
    return cv.u;
}
__device__ inline void split2(float x, unsigned short& h, unsigned short& l) {
    h = bf16_rne(x);
    l = bf16_rne(x - __uint_as_float((unsigned int)h << 16));
}

// ---------- CSR build ----------
__global__ void deg_count_k(const int* __restrict__ dst, int* __restrict__ deg, int E) {
    int i = blockIdx.x * blockDim.x + threadIdx.x;
    if (i < E) atomicAdd(&deg[dst[i]], 1);
}

__global__ void scan_part_k(const int* __restrict__ deg, int* __restrict__ incl,
                            int* __restrict__ blocksum, int N) {
    __shared__ int s[256];
    const int tid = threadIdx.x;
    const int i = blockIdx.x * 256 + tid;
    int v = (i < N) ? deg[i] : 0;
    s[tid] = v;
    __syncthreads();
    #pragma unroll
    for (int off = 1; off < 256; off <<= 1) {
        int t = (tid >= off) ? s[tid - off] : 0;
        __syncthreads();
        s[tid] += t;
        __syncthreads();
    }
    if (i < N) incl[i] = s[tid];
    if (tid == 255) blocksum[blockIdx.x] = s[255];
}

__global__ void scan_block_k(int* __restrict__ blocksum, int NB) {
    __shared__ int s[256];
    const int tid = threadIdx.x;
    int v = (tid < NB) ? blocksum[tid] : 0;
    s[tid] = v;
    __syncthreads();
    #pragma unroll
    for (int off = 1; off < 256; off <<= 1) {
        int t = (tid >= off) ? s[tid - off] : 0;
        __syncthreads();
        s[tid] += t;
        __syncthreads();
    }
    if (tid < NB) blocksum[tid] = s[tid] - v;   // exclusive
}

__global__ void scan_final_k(const int* __restrict__ deg, const int* __restrict__ incl,
                             const int* __restrict__ blocksum, int* __restrict__ rowptr,
                             float* __restrict__ dis, int N, int E) {
    const int i = blockIdx.x * 256 + threadIdx.x;
    if (i < N) {
        rowptr[i] = blocksum[blockIdx.x] + incl[i] - deg[i];
        dis[i] = rsqrtf((float)deg[i] + 1.0f);
    }
    if (i == 0) rowptr[N] = E;
}

__global__ void fill_csr_k(const int* __restrict__ src, const int* __restrict__ dst,
                           const int* __restrict__ rowptr, int* __restrict__ cursor,
                           int* __restrict__ csr, int E) {
    int e = blockIdx.x * blockDim.x + threadIdx.x;
    if (e < E) {
        const int d = dst[e];
        const int pos = rowptr[d] + atomicAdd(&cursor[d], 1);
        csr[pos] = src[e];
    }
}

// ---------- weight pack: fp32 W[128][128] -> MFMA-fragment-order bf16 hi/lo ----------
// frag (s,c): element (lane,j) = W[k][col], col = c*16 + (lane&15), k = s*32 + (lane>>4)*8 + j
// stored at idx = (s*8+c)*512 + lane*8 + j
__global__ void pack_w_k(const float* __restrict__ W, unsigned short* __restrict__ hi,
                         unsigned short* __restrict__ lo) {
    const int idx = blockIdx.x * 256 + threadIdx.x;   // 16384 total
    const int frag = idx >> 9;
    const int r = idx & 511;
    const int lane = r >> 3, j = r & 7;
    const int c = frag & 7, s = frag >> 3;
    const int col = (c << 4) | (lane & 15);
    const int k = (s << 5) + ((lane >> 4) << 3) + j;
    const float w = W[k * HDIM + col];
    unsigned short h, l;
    split2(w, h, l);
    hi[idx] = h;
    lo[idx] = l;
}

// ---------- X fp32 -> bf16 hi/lo (row-major) ----------
__global__ void prep_x_k(const float* __restrict__ X, unsigned short* __restrict__ hi,
                         unsigned short* __restrict__ lo, int total4) {
    int i = blockIdx.x * blockDim.x + threadIdx.x;
    if (i >= total4) return;
    const float4 v = reinterpret_cast<const float4*>(X)[i];
    ushort4 h, l;
    split2(v.x, h.x, l.x);
    split2(v.y, h.y, l.y);
    split2(v.z, h.z, l.z);
    split2(v.w, h.w, l.w);
    reinterpret_cast<ushort4*>(hi)[i] = h;
    reinterpret_cast<ushort4*>(lo)[i] = l;
}

// ---------- MFMA GEMM: hs = (X @ W) * dis[row], X = Xh+Xl bf16 pair ----------
// block: 256 thr = 4 waves, 64 rows; W (hi+lo) staged in 64KB LDS in frag order
__global__ __launch_bounds__(256) void mfma_gemm_k(
    const unsigned short* __restrict__ Xh, const unsigned short* __restrict__ Xl,
    const unsigned short* __restrict__ Wp, const float* __restrict__ dis,
    float* __restrict__ hs, int N) {
    __shared__ __align__(16) unsigned short wlds[32768];   // 64 KB: hi [0,16384), lo [16384,32768)
    const int tid = threadIdx.x;
    {
        const float4* wsrc = reinterpret_cast<const float4*>(Wp);
        float4* wdst = reinterpret_cast<float4*>(wlds);
        #pragma unroll
        for (int i = 0; i < 16; ++i) wdst[tid + i * 256] = wsrc[tid + i * 256];
    }
    __syncthreads();

    const int wave = tid >> 6, lane = tid & 63;
    const int row0 = (blockIdx.x << 6) + (wave << 4);
    if (row0 >= N) return;                 // N % 16 == 0: tiles fully in or out
    const int lrow = lane & 15;
    const int kgrp = (lane >> 4) << 3;     // 0,8,16,24

    const long abase = ((long)(row0 + lrow) << 7) + kgrp;
    bf16x8_t ah[4], al[4];
    #pragma unroll
    for (int s = 0; s < 4; ++s) {
        ah[s] = *reinterpret_cast<const bf16x8_t*>(Xh + abase + (s << 5));
        al[s] = *reinterpret_cast<const bf16x8_t*>(Xl + abase + (s << 5));
    }

    f32x4_t acc[8];
    #pragma unroll
    for (int c = 0; c < 8; ++c) acc[c] = (f32x4_t){0.f, 0.f, 0.f, 0.f};

    #pragma unroll
    for (int s = 0; s < 4; ++s) {
        #pragma unroll
        for (int c = 0; c < 8; ++c) {
            const int fo = (((s << 3) + c) << 9) + (lane << 3);
            const bf16x8_t bh = *reinterpret_cast<const bf16x8_t*>(wlds + fo);
            const bf16x8_t bl = *reinterpret_cast<const bf16x8_t*>(wlds + 16384 + fo);
            acc[c] = __builtin_amdgcn_mfma_f32_16x16x32_bf16(ah[s], bh, acc[c], 0, 0, 0);
            acc[c] = __builtin_amdgcn_mfma_f32_16x16x32_bf16(al[s], bh, acc[c], 0, 0, 0);
            acc[c] = __builtin_amdgcn_mfma_f32_16x16x32_bf16(ah[s], bl, acc[c], 0, 0, 0);
        }
    }

    // C/D: row = (lane>>4)*4 + i, col = c*16 + (lane&15)
    const int rbase = row0 + ((lane >> 4) << 2);
    float d[4];
    #pragma unroll
    for (int i = 0; i < 4; ++i) d[i] = dis[rbase + i];
    #pragma unroll
    for (int c = 0; c < 8; ++c) {
        const int col = (c << 4) | lrow;
        #pragma unroll
        for (int i = 0; i < 4; ++i)
            hs[((long)(rbase + i) << 7) + col] = acc[c][i] * d[i];
    }
}

// ---------- gather-aggregate: one wave per node, bf16 hi/lo output ----------
__global__ __launch_bounds__(256) void gather_agg_k(
    const int* __restrict__ rowptr, const int* __restrict__ csr,
    const float* __restrict__ hs, const float* __restrict__ dis,
    const float* __restrict__ b, unsigned short* __restrict__ oh,
    unsigned short* __restrict__ ol, int N) {
    const int lane = threadIdx.x & 63;
    const int wid = (int)((blockIdx.x * (long)blockDim.x + threadIdx.x) >> 6);
    const int nw = (int)(((long)gridDim.x * blockDim.x) >> 6);
    const float2 bb = *reinterpret_cast<const float2*>(&b[lane * 2]);
    for (int n = wid; n < N; n += nw) {
        const int r0 = rowptr[n], r1 = rowptr[n + 1];
        float2 acc = *reinterpret_cast<const float2*>(&hs[((long)n << 7) + lane * 2]);
        int e = r0;
        for (; e + 2 <= r1; e += 2) {
            const int s0 = csr[e], s1 = csr[e + 1];
            const float2 v0 = *reinterpret_cast<const float2*>(&hs[((long)s0 << 7) + lane * 2]);
            const float2 v1 = *reinterpret_cast<const float2*>(&hs[((long)s1 << 7) + lane * 2]);
            acc.x += v0.x + v1.x;
            acc.y += v0.y + v1.y;
        }
        if (e < r1) {
            const int s0 = csr[e];
            const float2 v0 = *reinterpret_cast<const float2*>(&hs[((long)s0 << 7) + lane * 2]);
            acc.x += v0.x;
            acc.y += v0.y;
        }
        const float dv = dis[n];
        const float o0 = fmaxf(fmaf(acc.x, dv, bb.x), 0.f);
        const float o1 = fmaxf(fmaf(acc.y, dv, bb.y), 0.f);
        ushort2 h, l;
        split2(o0, h.x, l.x);
        split2(o1, h.y, l.y);
        *reinterpret_cast<ushort2*>(oh + ((long)n << 7) + lane * 2) = h;
        *reinterpret_cast<ushort2*>(ol + ((long)n << 7) + lane * 2) = l;
    }
}

// ---------- Q head: h stored as bf16 hi/lo, reconstruct hi+lo ----------
__global__ __launch_bounds__(256) void qhead_k(
    const unsigned short* __restrict__ hh, const unsigned short* __restrict__ hl,
    const int* __restrict__ va, const float* __restrict__ Wq,
    const float* __restrict__ bq, float* __restrict__ out, int A) {
    const int lane = threadIdx.x & 63;
    int w = (int)((blockIdx.x * (long)blockDim.x + threadIdx.x) >> 6);
    const int nw = (int)(((long)gridDim.x * blockDim.x) >> 6);
    const float2 wu = *reinterpret_cast<const float2*>(&Wq[lane * 2]);
    const float2 wv = *reinterpret_cast<const float2*>(&Wq[HDIM + lane * 2]);
    const float bqv = bq[0];
    for (int a = w; a < A; a += nw) {
        const int u = va[2 * a], v = va[2 * a + 1];
        unsigned int ph = *reinterpret_cast<const unsigned int*>(hh + ((long)u << 7) + (lane << 1));
        unsigned int pl = *reinterpret_cast<const unsigned int*>(hl + ((long)u << 7) + (lane << 1));
        const float u0 = bf16u_to_f(ph) + bf16u_to_f(pl);
        const float u1 = __uint_as_float(ph & 0xffff0000u) + __uint_as_float(pl & 0xffff0000u);
        ph = *reinterpret_cast<const unsigned int*>(hh + ((long)v << 7) + (lane << 1));
        pl = *reinterpret_cast<const unsigned int*>(hl + ((long)v << 7) + (lane << 1));
        const float v0 = bf16u_to_f(ph) + bf16u_to_f(pl);
        const float v1 = __uint_as_float(ph & 0xffff0000u) + __uint_as_float(pl & 0xffff0000u);
        float s = u0 * wu.x + u1 * wu.y + v0 * wv.x + v1 * wv.y;
        #pragma unroll
        for (int off = 32; off > 0; off >>= 1) s += __shfl_down(s, off, 64);
        if (lane == 0) out[a] = s + bqv;
    }
}

extern "C" void kernel_launch(void* const* d_in, const int* in_sizes, int n_in,
                              void* d_out, int out_size, void* d_ws, size_t ws_size,
                              hipStream_t stream) {
    const float* x   = (const float*)d_in[0];
    const int*   ei  = (const int*)d_in[1];     // [2][E] flat: src then dst
    const int*   va  = (const int*)d_in[2];     // [A][2]
    const float* W1  = (const float*)d_in[3];
    const float* b1  = (const float*)d_in[4];
    const float* W2  = (const float*)d_in[5];
    const float* b2  = (const float*)d_in[6];
    const float* Wq  = (const float*)d_in[7];
    const float* bq  = (const float*)d_in[8];
    float* out = (float*)d_out;

    const int N = in_sizes[0] / HDIM;       // 50000
    const int E = in_sizes[1] / 2;          // 600000
    const int A = in_sizes[2] / 2;          // 200000
    const int* esrc = ei;
    const int* edst = ei + E;

    char* p = (char*)d_ws;
    auto alloc = [&](size_t bytes) { char* r = p; p += (bytes + 255) & ~(size_t)255; return r; };
    int* deg_i    = (int*)alloc((size_t)N * 4);
    int* incl     = (int*)alloc((size_t)N * 4);
    int* rowptr   = (int*)alloc((size_t)(N + 1) * 4);
    int* cursor   = (int*)alloc((size_t)N * 4);
    int* blocksum = (int*)alloc(256 * 4);
    int* csr      = (int*)alloc((size_t)E * 4);
    float* dis    = (float*)alloc((size_t)N * 4);
    unsigned short* Wp1 = (unsigned short*)alloc(32768 * 2);
    unsigned short* Wp2 = (unsigned short*)alloc(32768 * 2);
    unsigned short* Xh  = (unsigned short*)alloc((size_t)N * HDIM * 2);
    unsigned short* Xl  = (unsigned short*)alloc((size_t)N * HDIM * 2);
    float* bufA   = (float*)alloc((size_t)N * HDIM * 4);

    const int T = 256;
    const int NB = (N + 255) / 256;          // 196 (<= 256 required by scan_block_k)

    // --- CSR build + norms ---
    hipMemsetAsync(deg_i, 0, (size_t)N * 4, stream);
    hipMemsetAsync(cursor, 0, (size_t)N * 4, stream);
    deg_count_k<<<(E + T - 1) / T, T, 0, stream>>>(edst, deg_i, E);
    scan_part_k<<<NB, 256, 0, stream>>>(deg_i, incl, blocksum, N);
    scan_block_k<<<1, 256, 0, stream>>>(blocksum, NB);
    scan_final_k<<<NB, 256, 0, stream>>>(deg_i, incl, blocksum, rowptr, dis, N, E);
    fill_csr_k<<<(E + T - 1) / T, T, 0, stream>>>(esrc, edst, rowptr, cursor, csr, E);

    // --- weight pack + X split (cheap, once per call) ---
    pack_w_k<<<64, 256, 0, stream>>>(W1, Wp1, Wp1 + 16384);
    pack_w_k<<<64, 256, 0, stream>>>(W2, Wp2, Wp2 + 16384);
    prep_x_k<<<(N * HDIM / 4 + T - 1) / T, T, 0, stream>>>(x, Xh, Xl, N * HDIM / 4);

    // --- layer 1 ---
    mfma_gemm_k<<<(N + 63) / 64, 256, 0, stream>>>(Xh, Xl, Wp1, dis, bufA, N);
    gather_agg_k<<<2048, T, 0, stream>>>(rowptr, csr, bufA, dis, b1, Xh, Xl, N);   // h1 -> Xh/Xl

    // --- layer 2 ---
    mfma_gemm_k<<<(N + 63) / 64, 256, 0, stream>>>(Xh, Xl, Wp2, dis, bufA, N);
    gather_agg_k<<<2048, T, 0, stream>>>(rowptr, csr, bufA, dis, b2, Xh, Xl, N);   // h2 -> Xh/Xl

    // --- Q head ---
    qhead_k<<<4096, T, 0, stream>>>(Xh, Xl, va, Wq, bq, out, A);
}

// Round 7
// 297.130 us; speedup vs baseline: 8.2934x; 1.0817x over previous
//
#include <hip/hip_runtime.h>
#include <hip/hip_bf16.h>

#define HDIM 128

typedef __attribute__((ext_vector_type(8))) short bf16x8_t;
typedef __attribute__((ext_vector_type(4))) float f32x4_t;

// ---------- helpers ----------
__device__ inline float bf16u_to_f(unsigned int u) { return __uint_as_float(u << 16); }
__device__ inline unsigned short bf16_rne(float x) {
    union { __hip_bfloat16 b; unsigned short u; } cv;
    cv.b = __float2bfloat16(x);
    return cv.u;
}
__device__ inline void split2(float x, unsigned short& h, unsigned short& l) {
    h = bf16_rne(x);
    l = bf16_rne(x - __uint_as_float((unsigned int)h << 16));
}

// ---------- CSR build ----------
__global__ void deg_count_k(const int* __restrict__ dst, int* __restrict__ deg, int E) {
    int i = blockIdx.x * blockDim.x + threadIdx.x;
    if (i < E) atomicAdd(&deg[dst[i]], 1);
}

__global__ void scan_part_k(const int* __restrict__ deg, int* __restrict__ incl,
                            int* __restrict__ blocksum, int N) {
    __shared__ int s[256];
    const int tid = threadIdx.x;
    const int i = blockIdx.x * 256 + tid;
    int v = (i < N) ? deg[i] : 0;
    s[tid] = v;
    __syncthreads();
    #pragma unroll
    for (int off = 1; off < 256; off <<= 1) {
        int t = (tid >= off) ? s[tid - off] : 0;
        __syncthreads();
        s[tid] += t;
        __syncthreads();
    }
    if (i < N) incl[i] = s[tid];
    if (tid == 255) blocksum[blockIdx.x] = s[255];
}

__global__ void scan_block_k(int* __restrict__ blocksum, int NB) {
    __shared__ int s[256];
    const int tid = threadIdx.x;
    int v = (tid < NB) ? blocksum[tid] : 0;
    s[tid] = v;
    __syncthreads();
    #pragma unroll
    for (int off = 1; off < 256; off <<= 1) {
        int t = (tid >= off) ? s[tid - off] : 0;
        __syncthreads();
        s[tid] += t;
        __syncthreads();
    }
    if (tid < NB) blocksum[tid] = s[tid] - v;   // exclusive
}

__global__ void scan_final_k(const int* __restrict__ deg, const int* __restrict__ incl,
                             const int* __restrict__ blocksum, int* __restrict__ rowptr,
                             float* __restrict__ dis, int N, int E) {
    const int i = blockIdx.x * 256 + threadIdx.x;
    if (i < N) {
        rowptr[i] = blocksum[blockIdx.x] + incl[i] - deg[i];
        dis[i] = rsqrtf((float)deg[i] + 1.0f);
    }
    if (i == 0) rowptr[N] = E;
}

__global__ void fill_csr_k(const int* __restrict__ src, const int* __restrict__ dst,
                           const int* __restrict__ rowptr, int* __restrict__ cursor,
                           int* __restrict__ csr, int E) {
    int e = blockIdx.x * blockDim.x + threadIdx.x;
    if (e < E) {
        const int d = dst[e];
        const int pos = rowptr[d] + atomicAdd(&cursor[d], 1);
        csr[pos] = src[e];
    }
}

// ---------- weight pack: fp32 W[128][128] -> MFMA-fragment-order bf16 hi/lo ----------
__global__ void pack_w_k(const float* __restrict__ W, unsigned short* __restrict__ hi,
                         unsigned short* __restrict__ lo) {
    const int idx = blockIdx.x * 256 + threadIdx.x;   // 16384 total
    const int frag = idx >> 9;
    const int r = idx & 511;
    const int lane = r >> 3, j = r & 7;
    const int c = frag & 7, s = frag >> 3;
    const int col = (c << 4) | (lane & 15);
    const int k = (s << 5) + ((lane >> 4) << 3) + j;
    const float w = W[k * HDIM + col];
    unsigned short h, l;
    split2(w, h, l);
    hi[idx] = h;
    lo[idx] = l;
}

// ---------- X fp32 -> bf16 hi/lo (row-major) ----------
__global__ void prep_x_k(const float* __restrict__ X, unsigned short* __restrict__ hi,
                         unsigned short* __restrict__ lo, int total4) {
    int i = blockIdx.x * blockDim.x + threadIdx.x;
    if (i >= total4) return;
    const float4 v = reinterpret_cast<const float4*>(X)[i];
    ushort4 h, l;
    split2(v.x, h.x, l.x);
    split2(v.y, h.y, l.y);
    split2(v.z, h.z, l.z);
    split2(v.w, h.w, l.w);
    reinterpret_cast<ushort4*>(hi)[i] = h;
    reinterpret_cast<ushort4*>(lo)[i] = l;
}

// ---------- MFMA GEMM: hs = (X @ W) * dis[row], X = Xh+Xl bf16 pair ----------
__global__ __launch_bounds__(256) void mfma_gemm_k(
    const unsigned short* __restrict__ Xh, const unsigned short* __restrict__ Xl,
    const unsigned short* __restrict__ Wp, const float* __restrict__ dis,
    float* __restrict__ hs, int N) {
    __shared__ __align__(16) unsigned short wlds[32768];   // 64 KB: hi, lo
    const int tid = threadIdx.x;
    {
        const float4* wsrc = reinterpret_cast<const float4*>(Wp);
        float4* wdst = reinterpret_cast<float4*>(wlds);
        #pragma unroll
        for (int i = 0; i < 16; ++i) wdst[tid + i * 256] = wsrc[tid + i * 256];
    }
    __syncthreads();

    const int wave = tid >> 6, lane = tid & 63;
    const int row0 = (blockIdx.x << 6) + (wave << 4);
    if (row0 >= N) return;
    const int lrow = lane & 15;
    const int kgrp = (lane >> 4) << 3;

    const long abase = ((long)(row0 + lrow) << 7) + kgrp;
    bf16x8_t ah[4], al[4];
    #pragma unroll
    for (int s = 0; s < 4; ++s) {
        ah[s] = *reinterpret_cast<const bf16x8_t*>(Xh + abase + (s << 5));
        al[s] = *reinterpret_cast<const bf16x8_t*>(Xl + abase + (s << 5));
    }

    f32x4_t acc[8];
    #pragma unroll
    for (int c = 0; c < 8; ++c) acc[c] = (f32x4_t){0.f, 0.f, 0.f, 0.f};

    #pragma unroll
    for (int s = 0; s < 4; ++s) {
        #pragma unroll
        for (int c = 0; c < 8; ++c) {
            const int fo = (((s << 3) + c) << 9) + (lane << 3);
            const bf16x8_t bh = *reinterpret_cast<const bf16x8_t*>(wlds + fo);
            const bf16x8_t bl = *reinterpret_cast<const bf16x8_t*>(wlds + 16384 + fo);
            acc[c] = __builtin_amdgcn_mfma_f32_16x16x32_bf16(ah[s], bh, acc[c], 0, 0, 0);
            acc[c] = __builtin_amdgcn_mfma_f32_16x16x32_bf16(al[s], bh, acc[c], 0, 0, 0);
            acc[c] = __builtin_amdgcn_mfma_f32_16x16x32_bf16(ah[s], bl, acc[c], 0, 0, 0);
        }
    }

    const int rbase = row0 + ((lane >> 4) << 2);
    float d[4];
    #pragma unroll
    for (int i = 0; i < 4; ++i) d[i] = dis[rbase + i];
    #pragma unroll
    for (int c = 0; c < 8; ++c) {
        const int col = (c << 4) | lrow;
        #pragma unroll
        for (int i = 0; i < 4; ++i)
            hs[((long)(rbase + i) << 7) + col] = acc[c][i] * d[i];
    }
}

// ---------- gather-aggregate: one wave per node, 4-deep edge unroll ----------
__global__ __launch_bounds__(256) void gather_agg_k(
    const int* __restrict__ rowptr, const int* __restrict__ csr,
    const float* __restrict__ hs, const float* __restrict__ dis,
    const float* __restrict__ b, unsigned short* __restrict__ oh,
    unsigned short* __restrict__ ol, int N) {
    const int lane = threadIdx.x & 63;
    const int wid = (int)((blockIdx.x * (long)blockDim.x + threadIdx.x) >> 6);
    const int nw = (int)(((long)gridDim.x * blockDim.x) >> 6);
    const float2 bb = *reinterpret_cast<const float2*>(&b[lane * 2]);
    const int loff = lane * 2;
    for (int n = wid; n < N; n += nw) {
        const int r0 = rowptr[n], r1 = rowptr[n + 1];
        float2 acc = *reinterpret_cast<const float2*>(&hs[((long)n << 7) + loff]);
        float2 acc2 = {0.f, 0.f};
        int e = r0;
        for (; e + 4 <= r1; e += 4) {
            const int s0 = csr[e], s1 = csr[e + 1], s2 = csr[e + 2], s3 = csr[e + 3];
            const float2 v0 = *reinterpret_cast<const float2*>(&hs[((long)s0 << 7) + loff]);
            const float2 v1 = *reinterpret_cast<const float2*>(&hs[((long)s1 << 7) + loff]);
            const float2 v2 = *reinterpret_cast<const float2*>(&hs[((long)s2 << 7) + loff]);
            const float2 v3 = *reinterpret_cast<const float2*>(&hs[((long)s3 << 7) + loff]);
            acc.x += v0.x + v1.x;
            acc.y += v0.y + v1.y;
            acc2.x += v2.x + v3.x;
            acc2.y += v2.y + v3.y;
        }
        for (; e < r1; ++e) {
            const int s0 = csr[e];
            const float2 v0 = *reinterpret_cast<const float2*>(&hs[((long)s0 << 7) + loff]);
            acc.x += v0.x;
            acc.y += v0.y;
        }
        acc.x += acc2.x;
        acc.y += acc2.y;
        const float dv = dis[n];
        const float o0 = fmaxf(fmaf(acc.x, dv, bb.x), 0.f);
        const float o1 = fmaxf(fmaf(acc.y, dv, bb.y), 0.f);
        ushort2 h, l;
        split2(o0, h.x, l.x);
        split2(o1, h.y, l.y);
        *reinterpret_cast<ushort2*>(oh + ((long)n << 7) + loff) = h;
        *reinterpret_cast<ushort2*>(ol + ((long)n << 7) + loff) = l;
    }
}

// ---------- per-node projections: pu[n] = <h[n], Wq[0:128]>, pv[n] = <h[n], Wq[128:256]> ----------
__global__ __launch_bounds__(256) void proj_k(
    const unsigned short* __restrict__ hh, const unsigned short* __restrict__ hl,
    const float* __restrict__ Wq, float* __restrict__ pu, float* __restrict__ pv, int N) {
    const int lane = threadIdx.x & 63;
    const int wid = (int)((blockIdx.x * (long)blockDim.x + threadIdx.x) >> 6);
    const int nw = (int)(((long)gridDim.x * blockDim.x) >> 6);
    const float2 wu = *reinterpret_cast<const float2*>(&Wq[lane * 2]);
    const float2 wv = *reinterpret_cast<const float2*>(&Wq[HDIM + lane * 2]);
    for (int n = wid; n < N; n += nw) {
        const unsigned int ph = *reinterpret_cast<const unsigned int*>(hh + ((long)n << 7) + (lane << 1));
        const unsigned int pl = *reinterpret_cast<const unsigned int*>(hl + ((long)n << 7) + (lane << 1));
        const float h0 = bf16u_to_f(ph) + bf16u_to_f(pl);
        const float h1 = __uint_as_float(ph & 0xffff0000u) + __uint_as_float(pl & 0xffff0000u);
        float su = h0 * wu.x + h1 * wu.y;
        float sv = h0 * wv.x + h1 * wv.y;
        #pragma unroll
        for (int off = 32; off > 0; off >>= 1) {
            su += __shfl_down(su, off, 64);
            sv += __shfl_down(sv, off, 64);
        }
        if (lane == 0) {
            pu[n] = su;
            pv[n] = sv;
        }
    }
}

// ---------- Q head: out[a] = pu[va[a,0]] + pv[va[a,1]] + bq ----------
__global__ __launch_bounds__(256) void qhead_k(
    const float* __restrict__ pu, const float* __restrict__ pv,
    const int* __restrict__ va, const float* __restrict__ bq,
    float* __restrict__ out, int A) {
    const float bqv = bq[0];
    int i = blockIdx.x * blockDim.x + threadIdx.x;
    const int stride = gridDim.x * blockDim.x;
    for (; i < A; i += stride) {
        const int2 uv = reinterpret_cast<const int2*>(va)[i];
        out[i] = pu[uv.x] + pv[uv.y] + bqv;
    }
}

extern "C" void kernel_launch(void* const* d_in, const int* in_sizes, int n_in,
                              void* d_out, int out_size, void* d_ws, size_t ws_size,
                              hipStream_t stream) {
    const float* x   = (const float*)d_in[0];
    const int*   ei  = (const int*)d_in[1];     // [2][E] flat: src then dst
    const int*   va  = (const int*)d_in[2];     // [A][2]
    const float* W1  = (const float*)d_in[3];
    const float* b1  = (const float*)d_in[4];
    const float* W2  = (const float*)d_in[5];
    const float* b2  = (const float*)d_in[6];
    const float* Wq  = (const float*)d_in[7];
    const float* bq  = (const float*)d_in[8];
    float* out = (float*)d_out;

    const int N = in_sizes[0] / HDIM;       // 50000
    const int E = in_sizes[1] / 2;          // 600000
    const int A = in_sizes[2] / 2;          // 200000
    const int* esrc = ei;
    const int* edst = ei + E;

    char* p = (char*)d_ws;
    auto alloc = [&](size_t bytes) { char* r = p; p += (bytes + 255) & ~(size_t)255; return r; };
    int* deg_i    = (int*)alloc((size_t)N * 4);
    int* incl     = (int*)alloc((size_t)N * 4);
    int* rowptr   = (int*)alloc((size_t)(N + 1) * 4);
    int* cursor   = (int*)alloc((size_t)N * 4);
    int* blocksum = (int*)alloc(256 * 4);
    int* csr      = (int*)alloc((size_t)E * 4);
    float* dis    = (float*)alloc((size_t)N * 4);
    float* pu     = (float*)alloc((size_t)N * 4);
    float* pv     = (float*)alloc((size_t)N * 4);
    unsigned short* Wp1 = (unsigned short*)alloc(32768 * 2);
    unsigned short* Wp2 = (unsigned short*)alloc(32768 * 2);
    unsigned short* Xh  = (unsigned short*)alloc((size_t)N * HDIM * 2);
    unsigned short* Xl  = (unsigned short*)alloc((size_t)N * HDIM * 2);
    float* bufA   = (float*)alloc((size_t)N * HDIM * 4);

    const int T = 256;
    const int NB = (N + 255) / 256;          // 196 (<= 256 required by scan_block_k)

    // --- CSR build + norms ---
    hipMemsetAsync(deg_i, 0, (size_t)N * 4, stream);
    hipMemsetAsync(cursor, 0, (size_t)N * 4, stream);
    deg_count_k<<<(E + T - 1) / T, T, 0, stream>>>(edst, deg_i, E);
    scan_part_k<<<NB, 256, 0, stream>>>(deg_i, incl, blocksum, N);
    scan_block_k<<<1, 256, 0, stream>>>(blocksum, NB);
    scan_final_k<<<NB, 256, 0, stream>>>(deg_i, incl, blocksum, rowptr, dis, N, E);
    fill_csr_k<<<(E + T - 1) / T, T, 0, stream>>>(esrc, edst, rowptr, cursor, csr, E);

    // --- weight pack + X split ---
    pack_w_k<<<64, 256, 0, stream>>>(W1, Wp1, Wp1 + 16384);
    pack_w_k<<<64, 256, 0, stream>>>(W2, Wp2, Wp2 + 16384);
    prep_x_k<<<(N * HDIM / 4 + T - 1) / T, T, 0, stream>>>(x, Xh, Xl, N * HDIM / 4);

    // --- layer 1 ---
    mfma_gemm_k<<<(N + 63) / 64, 256, 0, stream>>>(Xh, Xl, Wp1, dis, bufA, N);
    gather_agg_k<<<2048, T, 0, stream>>>(rowptr, csr, bufA, dis, b1, Xh, Xl, N);   // h1 -> Xh/Xl

    // --- layer 2 ---
    mfma_gemm_k<<<(N + 63) / 64, 256, 0, stream>>>(Xh, Xl, Wp2, dis, bufA, N);
    gather_agg_k<<<2048, T, 0, stream>>>(rowptr, csr, bufA, dis, b2, Xh, Xl, N);   // h2 -> Xh/Xl

    // --- Q head: per-node projection then scalar gather ---
    proj_k<<<2048, T, 0, stream>>>(Xh, Xl, Wq, pu, pv, N);
    qhead_k<<<512, T, 0, stream>>>(pu, pv, va, bq, out, A);
}